// Round 9
// baseline (806.566 us; speedup 1.0000x reference)
//
#include <hip/hip_runtime.h>
#include <cstdint>
#include <cstddef>

#define N_NODESC 100000
#define N_EDGESC 400000
#define N_GRAPHSC 2048
#define F_INC 78
#define HEADS1C 10
#define D1C 78           // per-head out dim, layer 1
#define F1C 780          // HEADS1C * D1C
#define OUT2C 128
#define E_TOTC (N_EDGESC + N_NODESC)   // 500000 edges incl. self-loops

typedef unsigned short ushort_t;
typedef __attribute__((ext_vector_type(8))) short short8;
typedef __attribute__((ext_vector_type(4))) float f32x4;
typedef __attribute__((ext_vector_type(4))) unsigned int uint4v;
union U4S8 { uint4v u; short8 s; };

static __device__ __forceinline__ float lrelu(float x){ return x > 0.f ? x : 0.2f*x; }

// bf16 helpers (round-to-nearest-even)
static __device__ __forceinline__ unsigned short f2bf(float f){
  unsigned int u = __float_as_uint(f);
  unsigned int r = (u + 0x7fffu + ((u >> 16) & 1u)) >> 16;
  return (unsigned short)r;
}
static __device__ __forceinline__ float bf2f(unsigned short h){
  return __uint_as_float(((unsigned int)h) << 16);
}

// ---------------- CSR build ----------------
__global__ void k_deg(const int* __restrict__ ei, int* __restrict__ deg){
  int e = blockIdx.x*256 + threadIdx.x;
  if (e >= E_TOTC) return;
  int dst = (e < N_EDGESC) ? ei[N_EDGESC + e] : (e - N_EDGESC);
  atomicAdd(&deg[dst], 1);
}

__global__ __launch_bounds__(1024) void k_scan1(const int* __restrict__ deg,
                                                int* __restrict__ rowptr,
                                                int* __restrict__ bsum){
  __shared__ int s[1024];
  int t = threadIdx.x, i = blockIdx.x*1024 + t;
  int v = (i < N_NODESC) ? deg[i] : 0;
  s[t] = v; __syncthreads();
  for (int d = 1; d < 1024; d <<= 1){
    int xv = (t >= d) ? s[t-d] : 0;
    __syncthreads();
    s[t] += xv;
    __syncthreads();
  }
  if (i < N_NODESC) rowptr[i+1] = s[t];
  if (t == 1023) bsum[blockIdx.x] = s[t];
}

__global__ void k_scan2(int* __restrict__ bsum, int* __restrict__ rowptr, int nb){
  if (threadIdx.x == 0 && blockIdx.x == 0){
    int run = 0;
    for (int b = 0; b < nb; b++){ int v = bsum[b]; bsum[b] = run; run += v; }
    rowptr[0] = 0;
  }
}

__global__ __launch_bounds__(1024) void k_scan3(int* __restrict__ rowptr,
                                                const int* __restrict__ bsum){
  int i = blockIdx.x*1024 + threadIdx.x;
  if (i < N_NODESC) rowptr[i+1] += bsum[blockIdx.x];
}

__global__ void k_scatter(const int* __restrict__ ei, const int* __restrict__ rowptr,
                          int* __restrict__ cnt, int* __restrict__ esrc){
  int e = blockIdx.x*256 + threadIdx.x;
  if (e >= E_TOTC) return;
  int src, dst;
  if (e < N_EDGESC){ src = ei[e]; dst = ei[N_EDGESC + e]; }
  else { src = dst = e - N_EDGESC; }
  int pos = rowptr[dst] + atomicAdd(&cnt[dst], 1);
  esrc[pos] = src;
}

// canonicalize adjacency: sort each node's neighbor segment ascending.
// atomicAdd in k_scatter makes slot order launch-dependent; sorting makes the
// whole pipeline's fp32 accumulation order (and thus the output) deterministic
// across launches/graph replays. Equal srcs contribute identical terms, so
// their relative order is numerically irrelevant.
__global__ void k_sortadj(const int* __restrict__ rowptr, int* __restrict__ esrc){
  int n = blockIdx.x*256 + threadIdx.x;
  if (n >= N_NODESC) return;
  int b = rowptr[n], e = rowptr[n+1];
  for (int i = b + 1; i < e; i++){
    int v = esrc[i];
    int j = i - 1;
    while (j >= b && esrc[j] > v){ esrc[j+1] = esrc[j]; j--; }
    esrc[j+1] = v;
  }
}

// ---------------- layer-1 attention logit precompute ----------------
__global__ void k_wa1(const float* __restrict__ W1, const float* __restrict__ a_src1,
                      const float* __restrict__ a_dst1, float* __restrict__ Wa1){
  int i = blockIdx.x*256 + threadIdx.x;
  if (i >= F_INC*2*HEADS1C) return;
  int d = i / (2*HEADS1C), c = i % (2*HEADS1C);
  const float* a = (c < HEADS1C) ? a_src1 : a_dst1;
  int h = (c < HEADS1C) ? c : c - HEADS1C;
  float s = 0.f;
  for (int j = 0; j < D1C; j++) s += W1[d*F1C + h*D1C + j] * a[h*D1C + j];
  Wa1[d*(2*HEADS1C) + c] = s;
}

// att1[n*20 + h] = alpha_src[n,h];  att1[n*20 + 10 + h] = alpha_dst[n,h]
__global__ void k_att1(const float* __restrict__ x, const float* __restrict__ Wa1,
                       float* __restrict__ att1){
  int i = blockIdx.x*256 + threadIdx.x;
  if (i >= N_NODESC*2*HEADS1C) return;
  int n = i / (2*HEADS1C), c = i % (2*HEADS1C);
  const float* xr = x + (size_t)n*F_INC;
  float s = 0.f;
  for (int d = 0; d < F_INC; d++) s += xr[d] * Wa1[d*(2*HEADS1C) + c];
  att1[i] = s;
}

// per (node, head): max + 1/(sum exp + 1e-16), 4-edge-deep loads
__global__ void k_stats1(const float* __restrict__ att1, const int* __restrict__ rowptr,
                         const int* __restrict__ esrc, float* __restrict__ stat1){
  int i = blockIdx.x*256 + threadIdx.x;
  if (i >= N_NODESC*HEADS1C) return;
  int n = i / HEADS1C, h = i % HEADS1C;
  float ad = att1[n*20 + 10 + h];
  int b = rowptr[n], e = rowptr[n+1];
  float m = -1e30f;
  for (int p = b; p < e; p += 4){
    int c = e - p; if (c > 4) c = 4;
    float v[4];
    #pragma unroll
    for (int j = 0; j < 4; j++){ int s = esrc[p + (j < c ? j : 0)]; v[j] = att1[s*20 + h]; }
    #pragma unroll
    for (int j = 0; j < 4; j++) if (j < c) m = fmaxf(m, lrelu(v[j] + ad));
  }
  float den = 0.f;
  for (int p = b; p < e; p += 4){
    int c = e - p; if (c > 4) c = 4;
    float v[4];
    #pragma unroll
    for (int j = 0; j < 4; j++){ int s = esrc[p + (j < c ? j : 0)]; v[j] = att1[s*20 + h]; }
    #pragma unroll
    for (int j = 0; j < 4; j++) if (j < c) den += expf(lrelu(v[j] + ad) - m);
  }
  stat1[n*20 + h] = m;
  stat1[n*20 + 10 + h] = 1.f/(den + 1e-16f);
}

// one wave per node, 4-edge-deep: zc[local, h*78+d] = sum_e alpha[e,h]*x[src,d]
__global__ __launch_bounds__(64) void k_agg1(
    const float* __restrict__ x, const float* __restrict__ att1,
    const float* __restrict__ stat1, const int* __restrict__ rowptr,
    const int* __restrict__ esrc, ushort_t* __restrict__ zc, int base){
  __shared__ float xs[4][F_INC];
  __shared__ float al[4][HEADS1C];
  int n = base + blockIdx.x;
  int l = threadIdx.x;
  int b = rowptr[n], e = rowptr[n+1];
  float acc[13];
  #pragma unroll
  for (int k = 0; k < 13; k++) acc[k] = 0.f;
  int hk[13], dk[13];
  #pragma unroll
  for (int k = 0; k < 13; k++){ int f = l + 64*k; hk[k] = f/78; dk[k] = f%78; }
  float ad = 0.f, mm = 0.f, rd = 0.f;
  if (l < HEADS1C){
    ad = att1[n*20 + 10 + l];
    mm = stat1[n*20 + l];
    rd = stat1[n*20 + 10 + l];
  }
  for (int p = b; p < e; p += 4){
    int c = e - p; if (c > 4) c = 4;
    int ss[4];
    #pragma unroll
    for (int j = 0; j < 4; j++) ss[j] = esrc[p + (j < c ? j : 0)];
    if (l < 39){
      #pragma unroll
      for (int j = 0; j < 4; j++){
        float2 v = *(const float2*)(x + (size_t)ss[j]*F_INC + 2*l);
        xs[j][2*l] = v.x; xs[j][2*l+1] = v.y;
      }
    }
    if (l < HEADS1C){
      #pragma unroll
      for (int j = 0; j < 4; j++){
        float ev = lrelu(att1[ss[j]*20 + l] + ad);
        al[j][l] = (j < c) ? expf(ev - mm) * rd : 0.f;
      }
    }
    __syncthreads();
    #pragma unroll
    for (int k = 0; k < 13; k++){
      int f = l + 64*k;
      if (f < F1C){
        float s = al[0][hk[k]]*xs[0][dk[k]] + al[1][hk[k]]*xs[1][dk[k]]
                + al[2][hk[k]]*xs[2][dk[k]] + al[3][hk[k]]*xs[3][dk[k]];
        acc[k] += s;
      }
    }
    __syncthreads();
  }
  #pragma unroll
  for (int k = 0; k < 13; k++){
    int f = l + 64*k;
    if (f < F1C) zc[(size_t)blockIdx.x*F1C + f] = f2bf(acc[k]);
  }
}

// ---------------- weight pre-transpose (zero-padded bf16) ----------------
__global__ void k_prepW1(const float* __restrict__ W1, ushort_t* __restrict__ W1t){
  // W1t[h][n(80)][k(96)] = bf16(W1[k][h*78+n]) with zero pad
  int i = blockIdx.x*256 + threadIdx.x;
  if (i >= HEADS1C*80*96) return;
  int h = i / (80*96), rem = i % (80*96), n = rem / 96, k = rem % 96;
  float v = (n < D1C && k < F_INC) ? W1[(size_t)k*F1C + h*D1C + n] : 0.f;
  W1t[i] = f2bf(v);
}

// generic: Wt[n][k(KB)] = bf16(W[k][n]) zero-padded in k
__global__ void k_prepWt(const float* __restrict__ W, ushort_t* __restrict__ Wt,
                         int Kdim, int Ndim, int KB){
  int i = blockIdx.x*256 + threadIdx.x;
  if (i >= Ndim*KB) return;
  int n = i / KB, k = i % KB;
  float v = (k < Kdim) ? W[(size_t)k*Ndim + n] : 0.f;
  Wt[i] = f2bf(v);
}

__global__ void k_cast_bf(const float* __restrict__ in, ushort_t* __restrict__ o, int n){
  int i = blockIdx.x*256 + threadIdx.x;
  if (i < n) o[i] = f2bf(in[i]);
}

// ---------------- MFMA bf16 GEMM: C[M,N] = act(A @ Bt^T + bias), bf16 out ---
// A: bf16 [M rows, lda stride]; Bt: bf16 [BN][KB] zero-padded (KB % 32 == 0).
// KVAL = valid columns of the LAST 32-wide k-tile (even, 2..32). A-tail masked
// with compile-time dword masks AFTER a 16B load (deterministic regardless of
// overread garbage; keep >=8B slack after A).
template<int BN, int NT, int KB, int KVAL, int ACT, bool HASBIAS>
__global__ __launch_bounds__(256) void mfma_gemm(
    const ushort_t* __restrict__ A, const ushort_t* __restrict__ Bt,
    const float* __restrict__ bias, ushort_t* __restrict__ C,
    int M, int N, int lda, int ldc,
    int zsA, int zsBt, int zsC, int zsBias)
{
  __shared__ unsigned int As[64][20];   // 64 rows x 32 bf16 (+pad)
  __shared__ unsigned int Bs[BN][20];
  int z = blockIdx.z;
  A += (size_t)z*zsA; Bt += (size_t)z*zsBt; C += (size_t)z*zsC;
  const float* bz = HASBIAS ? (bias + (size_t)z*zsBias) : nullptr;
  int m0 = blockIdx.x*64;
  int n0 = blockIdx.y*BN;
  int t = threadIdx.x;
  int w = t >> 6, lane = t & 63;
  int q = lane >> 4, li = lane & 15;
  f32x4 acc[NT];
  #pragma unroll
  for (int i = 0; i < NT; i++) acc[i] = (f32x4){0.f,0.f,0.f,0.f};

  int am = t >> 2;           // staged row 0..63
  int ak0 = (t & 3)*8;       // short col base 0,8,16,24
  int gm = m0 + am;
  bool rv = (gm < M);

  #pragma unroll
  for (int ki = 0; ki < KB/32; ki++){
    const int kt = ki*32;
    // valid shorts this iter for this thread (compile-time per ki)
    int nv;
    if (ki == KB/32 - 1){
      int d = KVAL - ak0; nv = d < 0 ? 0 : (d > 8 ? 8 : d);
    } else nv = 8;
    {
      unsigned u0=0u, u1=0u, u2=0u, u3=0u;
      if (rv && nv > 0){
        const unsigned int* ap = (const unsigned int*)(A + (size_t)gm*lda + kt + ak0);
        u0 = ap[0]; u1 = ap[1]; u2 = ap[2]; u3 = ap[3];
        int ndw = nv >> 1;
        if (ndw < 4) u3 = 0u;
        if (ndw < 3) u2 = 0u;
        if (ndw < 2) u1 = 0u;
      }
      int c0 = (t & 3)*4;
      As[am][c0] = u0; As[am][c0+1] = u1; As[am][c0+2] = u2; As[am][c0+3] = u3;
    }
    for (int g = t; g < BN*4; g += 256){
      int n = g >> 2, c0 = (g & 3)*4;
      const unsigned int* bp = (const unsigned int*)(Bt + (size_t)(n0 + n)*KB + kt + c0*2);
      Bs[n][c0] = bp[0]; Bs[n][c0+1] = bp[1]; Bs[n][c0+2] = bp[2]; Bs[n][c0+3] = bp[3];
    }
    __syncthreads();
    U4S8 a; a.u = *(const uint4v*)&As[w*16 + li][q*4];
    #pragma unroll
    for (int nt = 0; nt < NT; nt++){
      U4S8 b; b.u = *(const uint4v*)&Bs[nt*16 + li][q*4];
      acc[nt] = __builtin_amdgcn_mfma_f32_16x16x32_bf16(a.s, b.s, acc[nt], 0, 0, 0);
    }
    __syncthreads();
  }
  #pragma unroll
  for (int nt = 0; nt < NT; nt++){
    int col = n0 + nt*16 + li;
    if (col >= N) continue;
    float bv = HASBIAS ? bz[col] : 0.f;
    #pragma unroll
    for (int r = 0; r < 4; r++){
      int gmr = m0 + w*16 + q*4 + r;
      if (gmr >= M) continue;
      float v = acc[nt][r] + bv;
      if (ACT == 1) v = fmaxf(v, 0.f);
      else if (ACT == 2) v = (v > 0.f) ? v : expm1f(v);
      C[(size_t)gmr*ldc + col] = f2bf(v);
    }
  }
}

// ---------------- layer-2 attention ----------------
__global__ void k_att2(const ushort_t* __restrict__ h2pre,
                       const float* __restrict__ a_src2,
                       const float* __restrict__ a_dst2, float* __restrict__ att2){
  int n = blockIdx.x*4 + (threadIdx.x >> 6);
  int l = threadIdx.x & 63;
  if (n >= N_NODESC) return;
  const ushort_t* r = h2pre + (size_t)n*OUT2C;
  float v0 = bf2f(r[l]), v1 = bf2f(r[64+l]);
  float p0 = v0*a_src2[l] + v1*a_src2[64+l];
  float p1 = v0*a_dst2[l] + v1*a_dst2[64+l];
  #pragma unroll
  for (int off = 32; off; off >>= 1){
    p0 += __shfl_xor(p0, off);
    p1 += __shfl_xor(p1, off);
  }
  if (l == 0){ att2[n*2] = p0; att2[n*2+1] = p1; }
}

// per node: max + 1/(sum exp), 4-edge-deep loads
__global__ void k_stats2(const float* __restrict__ att2, const int* __restrict__ rowptr,
                         const int* __restrict__ esrc, float* __restrict__ stat2){
  int n = blockIdx.x*256 + threadIdx.x;
  if (n >= N_NODESC) return;
  float ad = att2[n*2+1];
  int b = rowptr[n], e = rowptr[n+1];
  float m = -1e30f;
  for (int p = b; p < e; p += 4){
    int c = e - p; if (c > 4) c = 4;
    float v[4];
    #pragma unroll
    for (int j = 0; j < 4; j++){ int s = esrc[p + (j < c ? j : 0)]; v[j] = att2[s*2]; }
    #pragma unroll
    for (int j = 0; j < 4; j++) if (j < c) m = fmaxf(m, lrelu(v[j] + ad));
  }
  float den = 0.f;
  for (int p = b; p < e; p += 4){
    int c = e - p; if (c > 4) c = 4;
    float v[4];
    #pragma unroll
    for (int j = 0; j < 4; j++){ int s = esrc[p + (j < c ? j : 0)]; v[j] = att2[s*2]; }
    #pragma unroll
    for (int j = 0; j < 4; j++) if (j < c) den += expf(lrelu(v[j] + ad) - m);
  }
  stat2[n*2] = m;
  stat2[n*2+1] = 1.f/(den + 1e-16f);
}

// wave per node, 4-edge-deep coalesced pair gathers; fp32 h2 + sigmoid gate
__global__ void k_agg2(const ushort_t* __restrict__ h2pre,
                       const float* __restrict__ att2,
                       const float* __restrict__ stat2, const int* __restrict__ rowptr,
                       const int* __restrict__ esrc, const float* __restrict__ b2,
                       const float* __restrict__ w_gate, const float* __restrict__ b_gate,
                       float* __restrict__ h2, float* __restrict__ wnode){
  int n = blockIdx.x*4 + (threadIdx.x >> 6);
  int l = threadIdx.x & 63;
  if (n >= N_NODESC) return;
  float ad = att2[n*2+1], m = stat2[n*2], rd = stat2[n*2+1];
  int b = rowptr[n], e = rowptr[n+1];
  float a0 = 0.f, a1 = 0.f;
  for (int p = b; p < e; p += 4){
    int c = e - p; if (c > 4) c = 4;
    int ss[4];
    #pragma unroll
    for (int j = 0; j < 4; j++) ss[j] = esrc[p + (j < c ? j : 0)];
    unsigned u[4]; float at[4];
    #pragma unroll
    for (int j = 0; j < 4; j++) u[j] = *(const unsigned*)(h2pre + (size_t)ss[j]*OUT2C + 2*l);
    #pragma unroll
    for (int j = 0; j < 4; j++) at[j] = att2[ss[j]*2];
    #pragma unroll
    for (int j = 0; j < 4; j++){
      if (j < c){
        float alpha = expf(lrelu(at[j] + ad) - m) * rd;
        a0 += alpha * bf2f((ushort_t)(u[j] & 0xffffu));
        a1 += alpha * bf2f((ushort_t)(u[j] >> 16));
      }
    }
  }
  float v0 = fmaxf(a0 + b2[2*l],   0.f);
  float v1 = fmaxf(a1 + b2[2*l+1], 0.f);
  float2 hv; hv.x = v0; hv.y = v1;
  *(float2*)(h2 + (size_t)n*OUT2C + 2*l) = hv;
  float pp = v0*w_gate[2*l] + v1*w_gate[2*l+1];
  #pragma unroll
  for (int off = 32; off; off >>= 1) pp += __shfl_xor(pp, off);
  if (l == 0) wnode[n] = 1.f/(1.f + expf(-(pp + b_gate[0])));
}

// one block per graph: weighted-sum + max readout, bf16 out into xcb[:, 0:256]
__global__ __launch_bounds__(128) void k_readout(const float* __restrict__ h2,
                                                 const float* __restrict__ wnode,
                                                 const int* __restrict__ batch,
                                                 ushort_t* __restrict__ xcb){
  __shared__ int lohi[2];
  int g = blockIdx.x, t = threadIdx.x;
  if (t == 0){
    int lo = 0, hi = N_NODESC;
    while (lo < hi){ int mid = (lo+hi) >> 1; if (batch[mid] < g) lo = mid+1; else hi = mid; }
    lohi[0] = lo;
    int lo2 = lo; hi = N_NODESC;
    while (lo2 < hi){ int mid = (lo2+hi) >> 1; if (batch[mid] < g+1) lo2 = mid+1; else hi = mid; }
    lohi[1] = lo2;
  }
  __syncthreads();
  int lo = lohi[0], hi = lohi[1];
  float sum = 0.f, mx = 0.f;
  for (int n = lo; n < hi; n++){
    float v = h2[(size_t)n*OUT2C + t];
    sum += v * wnode[n];
    mx = fmaxf(mx, v);
  }
  xcb[(size_t)g*512 + t] = f2bf(sum);
  xcb[(size_t)g*512 + 128 + t] = f2bf(mx);
}

__global__ void k_final(const ushort_t* __restrict__ f2b, const float* __restrict__ W_out,
                        const float* __restrict__ b_out, float* __restrict__ out){
  int g = blockIdx.x*4 + (threadIdx.x >> 6);
  int l = threadIdx.x & 63;
  if (g >= N_GRAPHSC) return;
  float s = 0.f;
  #pragma unroll
  for (int k = 0; k < 4; k++) s += bf2f(f2b[(size_t)g*256 + l + 64*k]) * W_out[l + 64*k];
  #pragma unroll
  for (int off = 32; off; off >>= 1) s += __shfl_xor(s, off);
  if (l == 0) out[g] = s + b_out[0];
}

extern "C" void kernel_launch(void* const* d_in, const int* in_sizes, int n_in,
                              void* d_out, int out_size, void* d_ws, size_t ws_size,
                              hipStream_t stream) {
  const float* x      = (const float*)d_in[0];
  const int*   ei     = (const int*)d_in[1];
  const int*   batch  = (const int*)d_in[2];
  const float* target = (const float*)d_in[3];
  const float* W1     = (const float*)d_in[4];
  const float* a_src1 = (const float*)d_in[5];
  const float* a_dst1 = (const float*)d_in[6];
  const float* b1     = (const float*)d_in[7];
  const float* W2     = (const float*)d_in[8];
  const float* a_src2 = (const float*)d_in[9];
  const float* a_dst2 = (const float*)d_in[10];
  const float* b2     = (const float*)d_in[11];
  const float* w_gate = (const float*)d_in[12];
  const float* b_gate = (const float*)d_in[13];
  const float* W_xt   = (const float*)d_in[14];
  const float* b_xt   = (const float*)d_in[15];
  const float* W_fc1  = (const float*)d_in[16];
  const float* b_fc1  = (const float*)d_in[17];
  const float* W_fc2  = (const float*)d_in[18];
  const float* b_fc2  = (const float*)d_in[19];
  const float* W_out  = (const float*)d_in[20];
  const float* b_out  = (const float*)d_in[21];
  float* out = (float*)d_out;

  // ---- adaptive chunking so the carve fits ws_size (same thresholds as R7) --
  const size_t MB = (size_t)1 << 20;
  int C;
  if      (ws_size >= 410*MB) C = 1;
  else if (ws_size >= 245*MB) C = 2;
  else if (ws_size >= 165*MB) C = 4;
  else                        C = 8;
  const int R = N_NODESC / C;

  char* p = (char*)d_ws;
  auto carve = [&](size_t bytes) -> char* {
    char* r = p; p += (bytes + 255) & ~(size_t)255; return r;
  };
  int*   deg    = (int*)  carve((size_t)N_NODESC*4);
  int*   rowptr = (int*)  carve((size_t)(N_NODESC+1)*4);
  int*   cnt    = (int*)  carve((size_t)N_NODESC*4);
  int*   esrc   = (int*)  carve((size_t)E_TOTC*4);
  int*   bsum   = (int*)  carve(128*4);
  float* Wa1    = (float*)carve((size_t)F_INC*20*4);
  float* att1   = (float*)carve((size_t)N_NODESC*20*4);
  float* stat1  = (float*)carve((size_t)N_NODESC*20*4);
  float* att2   = (float*)carve((size_t)N_NODESC*2*4);
  float* stat2  = (float*)carve((size_t)N_NODESC*2*4);
  float* wnode  = (float*)carve((size_t)N_NODESC*4);
  ushort_t* W1t   = (ushort_t*)carve((size_t)HEADS1C*80*96*2);
  ushort_t* W2t   = (ushort_t*)carve((size_t)OUT2C*800*2);
  ushort_t* Wxtt  = (ushort_t*)carve((size_t)256*1280*2);
  ushort_t* Wfc1t = (ushort_t*)carve((size_t)1024*512*2);
  ushort_t* Wfc2t = (ushort_t*)carve((size_t)256*1024*2);
  ushort_t* tb    = (ushort_t*)carve((size_t)N_GRAPHSC*1280*2);
  ushort_t* h2pre = (ushort_t*)carve((size_t)N_NODESC*OUT2C*2);
  ushort_t* xcb   = (ushort_t*)carve((size_t)N_GRAPHSC*512*2);
  ushort_t* f1b   = (ushort_t*)carve((size_t)N_GRAPHSC*1024*2);
  ushort_t* f2b   = (ushort_t*)carve((size_t)N_GRAPHSC*256*2);
  size_t big_bytes = (size_t)R*F1C*2*2 + 4096;          // zc + h1c (bf16) + overread slack
  size_t h2_bytes  = (size_t)N_NODESC*OUT2C*4;          // h2 (fp32)
  char*  BIG = carve(big_bytes > h2_bytes ? big_bytes : h2_bytes);
  ushort_t* zc  = (ushort_t*)BIG;
  ushort_t* h1c = zc + (size_t)R*F1C;
  float* h2 = (float*)BIG;   // overlays zc/h1c AFTER layer-1/2 GEMMs are done

  hipMemsetAsync(deg, 0, (size_t)N_NODESC*4, stream);
  hipMemsetAsync(cnt, 0, (size_t)N_NODESC*4, stream);

  // CSR by destination (self-loops appended) + canonical neighbor order
  k_deg<<<(E_TOTC+255)/256, 256, 0, stream>>>(ei, deg);
  int nb = (N_NODESC + 1023)/1024;
  k_scan1<<<nb, 1024, 0, stream>>>(deg, rowptr, bsum);
  k_scan2<<<1, 64, 0, stream>>>(bsum, rowptr, nb);
  k_scan3<<<nb, 1024, 0, stream>>>(rowptr, bsum);
  k_scatter<<<(E_TOTC+255)/256, 256, 0, stream>>>(ei, rowptr, cnt, esrc);
  k_sortadj<<<(N_NODESC+255)/256, 256, 0, stream>>>(rowptr, esrc);

  // weight prep (bf16 transposed, zero-padded) + target cast
  k_prepW1<<<(HEADS1C*80*96+255)/256, 256, 0, stream>>>(W1, W1t);
  k_prepWt<<<(OUT2C*800+255)/256, 256, 0, stream>>>(W2, W2t, F1C, OUT2C, 800);
  k_prepWt<<<(256*1280+255)/256, 256, 0, stream>>>(W_xt, Wxtt, 1280, 256, 1280);
  k_prepWt<<<(1024*512+255)/256, 256, 0, stream>>>(W_fc1, Wfc1t, 512, 1024, 512);
  k_prepWt<<<(256*1024+255)/256, 256, 0, stream>>>(W_fc2, Wfc2t, 1024, 256, 1024);
  k_cast_bf<<<((N_GRAPHSC*1280)+255)/256, 256, 0, stream>>>(target, tb, N_GRAPHSC*1280);

  // layer-1 attention logits via folded weights
  k_wa1<<<(F_INC*20+255)/256, 256, 0, stream>>>(W1, a_src1, a_dst1, Wa1);
  k_att1<<<(N_NODESC*20+255)/256, 256, 0, stream>>>(x, Wa1, att1);
  k_stats1<<<(N_NODESC*HEADS1C+255)/256, 256, 0, stream>>>(att1, rowptr, esrc, stat1);

  // layer-1 (chunked): agg -> zc; MFMA per-head GEMM+b1+elu -> h1c; h1c@W2 -> h2pre
  for (int c = 0; c < C; c++){
    int base = c*R;
    k_agg1<<<R, 64, 0, stream>>>(x, att1, stat1, rowptr, esrc, zc, base);
    // K = 78 -> KB=96, KVAL=14 (cols 64..77 valid in last tile)
    mfma_gemm<80,5,96,14,2,true><<<dim3((R+63)/64, 1, HEADS1C), 256, 0, stream>>>(
        zc, W1t, b1, h1c, R, D1C, F1C, F1C,
        /*zsA*/D1C, /*zsBt*/80*96, /*zsC*/D1C, /*zsBias*/D1C);
    // K = 780 -> KB=800, KVAL=12 (cols 768..779 valid in last tile)
    mfma_gemm<128,8,800,12,0,false><<<dim3((R+63)/64, 1, 1), 256, 0, stream>>>(
        h1c, W2t, nullptr, h2pre + (size_t)base*OUT2C, R, OUT2C, F1C, OUT2C,
        0, 0, 0, 0);
  }

  // layer-2 attention + aggregation (h2 overlays the dead zc/h1c region)
  k_att2<<<(N_NODESC+3)/4, 256, 0, stream>>>(h2pre, a_src2, a_dst2, att2);
  k_stats2<<<(N_NODESC+255)/256, 256, 0, stream>>>(att2, rowptr, esrc, stat2);
  k_agg2<<<(N_NODESC+3)/4, 256, 0, stream>>>(h2pre, att2, stat2, rowptr, esrc,
                                             b2, w_gate, b_gate, h2, wnode);

  // readout (bf16) + MLP head via MFMA (K multiples of 32 -> KVAL=32, no masks)
  k_readout<<<N_GRAPHSC, 128, 0, stream>>>(h2, wnode, batch, xcb);
  mfma_gemm<128,8,1280,32,0,true><<<dim3(N_GRAPHSC/64, 256/128, 1), 256, 0, stream>>>(
      tb, Wxtt, b_xt, xcb + 256, N_GRAPHSC, 256, 1280, 512, 0,0,0,0);
  mfma_gemm<128,8,512,32,1,true><<<dim3(N_GRAPHSC/64, 1024/128, 1), 256, 0, stream>>>(
      xcb, Wfc1t, b_fc1, f1b, N_GRAPHSC, 1024, 512, 1024, 0,0,0,0);
  mfma_gemm<128,8,1024,32,1,true><<<dim3(N_GRAPHSC/64, 256/128, 1), 256, 0, stream>>>(
      f1b, Wfc2t, b_fc2, f2b, N_GRAPHSC, 256, 1024, 256, 0,0,0,0);
  k_final<<<(N_GRAPHSC+3)/4, 256, 0, stream>>>(f2b, W_out, b_out, out);
}

// Round 10
// 803.743 us; speedup vs baseline: 1.0035x; 1.0035x over previous
//
#include <hip/hip_runtime.h>
#include <cstdint>
#include <cstddef>

#define N_NODESC 100000
#define N_EDGESC 400000
#define N_GRAPHSC 2048
#define F_INC 78
#define HEADS1C 10
#define D1C 78           // per-head out dim, layer 1
#define F1C 780          // HEADS1C * D1C
#define OUT2C 128
#define E_TOTC (N_EDGESC + N_NODESC)   // 500000 edges incl. self-loops

typedef unsigned short ushort_t;
typedef __attribute__((ext_vector_type(8))) short short8;
typedef __attribute__((ext_vector_type(4))) float f32x4;
typedef __attribute__((ext_vector_type(4))) unsigned int uint4v;
union U4S8 { uint4v u; short8 s; };

static __device__ __forceinline__ float lrelu(float x){ return x > 0.f ? x : 0.2f*x; }

// bf16 helpers (round-to-nearest-even)
static __device__ __forceinline__ unsigned short f2bf(float f){
  unsigned int u = __float_as_uint(f);
  unsigned int r = (u + 0x7fffu + ((u >> 16) & 1u)) >> 16;
  return (unsigned short)r;
}
static __device__ __forceinline__ float bf2f(unsigned short h){
  return __uint_as_float(((unsigned int)h) << 16);
}

// ---------------- CSR build ----------------
__global__ void k_deg(const int* __restrict__ ei, int* __restrict__ deg){
  int e = blockIdx.x*256 + threadIdx.x;
  if (e >= E_TOTC) return;
  int dst = (e < N_EDGESC) ? ei[N_EDGESC + e] : (e - N_EDGESC);
  atomicAdd(&deg[dst], 1);
}

__global__ __launch_bounds__(1024) void k_scan1(const int* __restrict__ deg,
                                                int* __restrict__ rowptr,
                                                int* __restrict__ bsum){
  __shared__ int s[1024];
  int t = threadIdx.x, i = blockIdx.x*1024 + t;
  int v = (i < N_NODESC) ? deg[i] : 0;
  s[t] = v; __syncthreads();
  for (int d = 1; d < 1024; d <<= 1){
    int xv = (t >= d) ? s[t-d] : 0;
    __syncthreads();
    s[t] += xv;
    __syncthreads();
  }
  if (i < N_NODESC) rowptr[i+1] = s[t];
  if (t == 1023) bsum[blockIdx.x] = s[t];
}

__global__ void k_scan2(int* __restrict__ bsum, int* __restrict__ rowptr, int nb){
  if (threadIdx.x == 0 && blockIdx.x == 0){
    int run = 0;
    for (int b = 0; b < nb; b++){ int v = bsum[b]; bsum[b] = run; run += v; }
    rowptr[0] = 0;
  }
}

__global__ __launch_bounds__(1024) void k_scan3(int* __restrict__ rowptr,
                                                const int* __restrict__ bsum){
  int i = blockIdx.x*1024 + threadIdx.x;
  if (i < N_NODESC) rowptr[i+1] += bsum[blockIdx.x];
}

__global__ void k_scatter(const int* __restrict__ ei, const int* __restrict__ rowptr,
                          int* __restrict__ cnt, int* __restrict__ esrc){
  int e = blockIdx.x*256 + threadIdx.x;
  if (e >= E_TOTC) return;
  int src, dst;
  if (e < N_EDGESC){ src = ei[e]; dst = ei[N_EDGESC + e]; }
  else { src = dst = e - N_EDGESC; }
  int pos = rowptr[dst] + atomicAdd(&cnt[dst], 1);
  esrc[pos] = src;
}

// canonicalize adjacency (determinism across launches; see R9)
__global__ void k_sortadj(const int* __restrict__ rowptr, int* __restrict__ esrc){
  int n = blockIdx.x*256 + threadIdx.x;
  if (n >= N_NODESC) return;
  int b = rowptr[n], e = rowptr[n+1];
  for (int i = b + 1; i < e; i++){
    int v = esrc[i];
    int j = i - 1;
    while (j >= b && esrc[j] > v){ esrc[j+1] = esrc[j]; j--; }
    esrc[j+1] = v;
  }
}

// ---------------- layer-1 attention logit precompute ----------------
__global__ void k_wa1(const float* __restrict__ W1, const float* __restrict__ a_src1,
                      const float* __restrict__ a_dst1, float* __restrict__ Wa1){
  int i = blockIdx.x*256 + threadIdx.x;
  if (i >= F_INC*2*HEADS1C) return;
  int d = i / (2*HEADS1C), c = i % (2*HEADS1C);
  const float* a = (c < HEADS1C) ? a_src1 : a_dst1;
  int h = (c < HEADS1C) ? c : c - HEADS1C;
  float s = 0.f;
  for (int j = 0; j < D1C; j++) s += W1[d*F1C + h*D1C + j] * a[h*D1C + j];
  Wa1[d*(2*HEADS1C) + c] = s;
}

// att1[n*20 + h] = alpha_src[n,h];  att1[n*20 + 10 + h] = alpha_dst[n,h]
__global__ void k_att1(const float* __restrict__ x, const float* __restrict__ Wa1,
                       float* __restrict__ att1){
  int i = blockIdx.x*256 + threadIdx.x;
  if (i >= N_NODESC*2*HEADS1C) return;
  int n = i / (2*HEADS1C), c = i % (2*HEADS1C);
  const float* xr = x + (size_t)n*F_INC;
  float s = 0.f;
  for (int d = 0; d < F_INC; d++) s += xr[d] * Wa1[d*(2*HEADS1C) + c];
  att1[i] = s;
}

// per (node, head): ONLINE single-pass max+denom, 4-edge-deep loads
__global__ void k_stats1(const float* __restrict__ att1, const int* __restrict__ rowptr,
                         const int* __restrict__ esrc, float* __restrict__ stat1){
  int i = blockIdx.x*256 + threadIdx.x;
  if (i >= N_NODESC*HEADS1C) return;
  int n = i / HEADS1C, h = i % HEADS1C;
  float ad = att1[n*20 + 10 + h];
  int b = rowptr[n], e = rowptr[n+1];
  float m = -1e30f, den = 0.f;
  for (int p = b; p < e; p += 4){
    int c = e - p; if (c > 4) c = 4;
    float v[4];
    #pragma unroll
    for (int j = 0; j < 4; j++){ int s = esrc[p + (j < c ? j : 0)]; v[j] = att1[s*20 + h]; }
    #pragma unroll
    for (int j = 0; j < 4; j++){
      if (j < c){
        float ev = lrelu(v[j] + ad);
        float mn = fmaxf(m, ev);
        den = den*__expf(m - mn) + __expf(ev - mn);
        m = mn;
      }
    }
  }
  stat1[n*20 + h] = m;
  stat1[n*20 + 10 + h] = 1.f/(den + 1e-16f);
}

// one wave per node, 4-edge-deep: zc[local, h*78+d] = sum_e alpha[e,h]*x[src,d]
__global__ __launch_bounds__(64) void k_agg1(
    const float* __restrict__ x, const float* __restrict__ att1,
    const float* __restrict__ stat1, const int* __restrict__ rowptr,
    const int* __restrict__ esrc, ushort_t* __restrict__ zc, int base){
  __shared__ float xs[4][F_INC];
  __shared__ float al[4][HEADS1C];
  int n = base + blockIdx.x;
  int l = threadIdx.x;
  int b = rowptr[n], e = rowptr[n+1];
  float acc[13];
  #pragma unroll
  for (int k = 0; k < 13; k++) acc[k] = 0.f;
  int hk[13], dk[13];
  #pragma unroll
  for (int k = 0; k < 13; k++){ int f = l + 64*k; hk[k] = f/78; dk[k] = f%78; }
  float ad = 0.f, mm = 0.f, rd = 0.f;
  if (l < HEADS1C){
    ad = att1[n*20 + 10 + l];
    mm = stat1[n*20 + l];
    rd = stat1[n*20 + 10 + l];
  }
  for (int p = b; p < e; p += 4){
    int c = e - p; if (c > 4) c = 4;
    int ss[4];
    #pragma unroll
    for (int j = 0; j < 4; j++) ss[j] = esrc[p + (j < c ? j : 0)];
    if (l < 39){
      #pragma unroll
      for (int j = 0; j < 4; j++){
        float2 v = *(const float2*)(x + (size_t)ss[j]*F_INC + 2*l);
        xs[j][2*l] = v.x; xs[j][2*l+1] = v.y;
      }
    }
    if (l < HEADS1C){
      #pragma unroll
      for (int j = 0; j < 4; j++){
        float ev = lrelu(att1[ss[j]*20 + l] + ad);
        al[j][l] = (j < c) ? __expf(ev - mm) * rd : 0.f;
      }
    }
    __syncthreads();
    #pragma unroll
    for (int k = 0; k < 13; k++){
      int f = l + 64*k;
      if (f < F1C){
        float s = al[0][hk[k]]*xs[0][dk[k]] + al[1][hk[k]]*xs[1][dk[k]]
                + al[2][hk[k]]*xs[2][dk[k]] + al[3][hk[k]]*xs[3][dk[k]];
        acc[k] += s;
      }
    }
    __syncthreads();
  }
  #pragma unroll
  for (int k = 0; k < 13; k++){
    int f = l + 64*k;
    if (f < F1C) zc[(size_t)blockIdx.x*F1C + f] = f2bf(acc[k]);
  }
}

// ---------------- weight pre-transpose (zero-padded bf16) ----------------
__global__ void k_prepW1(const float* __restrict__ W1, ushort_t* __restrict__ W1t){
  // W1t[h][n(80)][k(96)] = bf16(W1[k][h*78+n]) with zero pad
  int i = blockIdx.x*256 + threadIdx.x;
  if (i >= HEADS1C*80*96) return;
  int h = i / (80*96), rem = i % (80*96), n = rem / 96, k = rem % 96;
  float v = (n < D1C && k < F_INC) ? W1[(size_t)k*F1C + h*D1C + n] : 0.f;
  W1t[i] = f2bf(v);
}

// generic: Wt[n][k(KB)] = bf16(W[k][n]) zero-padded in k
__global__ void k_prepWt(const float* __restrict__ W, ushort_t* __restrict__ Wt,
                         int Kdim, int Ndim, int KB){
  int i = blockIdx.x*256 + threadIdx.x;
  if (i >= Ndim*KB) return;
  int n = i / KB, k = i % KB;
  float v = (k < Kdim) ? W[(size_t)k*Ndim + n] : 0.f;
  Wt[i] = f2bf(v);
}

__global__ void k_cast_bf(const float* __restrict__ in, ushort_t* __restrict__ o, int n){
  int i = blockIdx.x*256 + threadIdx.x;
  if (i < n) o[i] = f2bf(in[i]);
}

// ---------------- MFMA bf16 GEMM: C[M,N] = act(A @ Bt^T + bias), bf16 out ---
// BM in {64,128}. With BM=128 each wave owns TWO 16-row groups sharing each
// B fragment (1 ds_read_b128 of B feeds 2 MFMAs). Bt zero-padded [BN][KB],
// KVAL masks the last k-tile after the (always 16B) load -> deterministic.
template<int BM, int BN, int NT, int KB, int KVAL, int ACT, bool HASBIAS>
__global__ __launch_bounds__(256) void mfma_gemm(
    const ushort_t* __restrict__ A, const ushort_t* __restrict__ Bt,
    const float* __restrict__ bias, ushort_t* __restrict__ C,
    int M, int N, int lda, int ldc,
    int zsA, int zsBt, int zsC, int zsBias)
{
  constexpr int RG = BM/64;
  __shared__ unsigned int As[BM][20];   // rows x 32 bf16 (+pad)
  __shared__ unsigned int Bs[BN][20];
  int z = blockIdx.z;
  A += (size_t)z*zsA; Bt += (size_t)z*zsBt; C += (size_t)z*zsC;
  const float* bz = HASBIAS ? (bias + (size_t)z*zsBias) : nullptr;
  int m0 = blockIdx.x*BM;
  int n0 = blockIdx.y*BN;
  int t = threadIdx.x;
  int w = t >> 6, lane = t & 63;
  int q = lane >> 4, li = lane & 15;
  f32x4 acc[RG][NT];
  #pragma unroll
  for (int rg = 0; rg < RG; rg++)
    #pragma unroll
    for (int i = 0; i < NT; i++) acc[rg][i] = (f32x4){0.f,0.f,0.f,0.f};

  int am = t >> 2;           // staged row base 0..63
  int ak0 = (t & 3)*8;       // short col base 0,8,16,24

  #pragma unroll
  for (int ki = 0; ki < KB/32; ki++){
    const int kt = ki*32;
    int nv;                  // valid shorts this iter (compile-time per ki)
    if (ki == KB/32 - 1){
      int d = KVAL - ak0; nv = d < 0 ? 0 : (d > 8 ? 8 : d);
    } else nv = 8;
    #pragma unroll
    for (int rg = 0; rg < RG; rg++){
      int row = am + rg*64;
      int gm = m0 + row;
      unsigned u0=0u, u1=0u, u2=0u, u3=0u;
      if (gm < M && nv > 0){
        const unsigned int* ap = (const unsigned int*)(A + (size_t)gm*lda + kt + ak0);
        u0 = ap[0]; u1 = ap[1]; u2 = ap[2]; u3 = ap[3];
        int ndw = nv >> 1;
        if (ndw < 4) u3 = 0u;
        if (ndw < 3) u2 = 0u;
        if (ndw < 2) u1 = 0u;
      }
      int c0 = (t & 3)*4;
      As[row][c0] = u0; As[row][c0+1] = u1; As[row][c0+2] = u2; As[row][c0+3] = u3;
    }
    for (int g = t; g < BN*4; g += 256){
      int n = g >> 2, c0 = (g & 3)*4;
      const unsigned int* bp = (const unsigned int*)(Bt + (size_t)(n0 + n)*KB + kt + c0*2);
      Bs[n][c0] = bp[0]; Bs[n][c0+1] = bp[1]; Bs[n][c0+2] = bp[2]; Bs[n][c0+3] = bp[3];
    }
    __syncthreads();
    U4S8 a[RG];
    #pragma unroll
    for (int rg = 0; rg < RG; rg++)
      a[rg].u = *(const uint4v*)&As[rg*64 + w*16 + li][q*4];
    #pragma unroll
    for (int nt = 0; nt < NT; nt++){
      U4S8 b; b.u = *(const uint4v*)&Bs[nt*16 + li][q*4];
      #pragma unroll
      for (int rg = 0; rg < RG; rg++)
        acc[rg][nt] = __builtin_amdgcn_mfma_f32_16x16x32_bf16(a[rg].s, b.s, acc[rg][nt], 0, 0, 0);
    }
    __syncthreads();
  }
  #pragma unroll
  for (int rg = 0; rg < RG; rg++){
    #pragma unroll
    for (int nt = 0; nt < NT; nt++){
      int col = n0 + nt*16 + li;
      if (col >= N) continue;
      float bv = HASBIAS ? bz[col] : 0.f;
      #pragma unroll
      for (int r = 0; r < 4; r++){
        int gmr = m0 + rg*64 + w*16 + q*4 + r;
        if (gmr >= M) continue;
        float v = acc[rg][nt][r] + bv;
        if (ACT == 1) v = fmaxf(v, 0.f);
        else if (ACT == 2) v = (v > 0.f) ? v : (__expf(v) - 1.f);  // fast ELU (v_exp_f32)
        C[(size_t)gmr*ldc + col] = f2bf(v);
      }
    }
  }
}

// ---------------- layer-2 attention ----------------
__global__ void k_att2(const ushort_t* __restrict__ h2pre,
                       const float* __restrict__ a_src2,
                       const float* __restrict__ a_dst2, float* __restrict__ att2){
  int n = blockIdx.x*4 + (threadIdx.x >> 6);
  int l = threadIdx.x & 63;
  if (n >= N_NODESC) return;
  const ushort_t* r = h2pre + (size_t)n*OUT2C;
  float v0 = bf2f(r[l]), v1 = bf2f(r[64+l]);
  float p0 = v0*a_src2[l] + v1*a_src2[64+l];
  float p1 = v0*a_dst2[l] + v1*a_dst2[64+l];
  #pragma unroll
  for (int off = 32; off; off >>= 1){
    p0 += __shfl_xor(p0, off);
    p1 += __shfl_xor(p1, off);
  }
  if (l == 0){ att2[n*2] = p0; att2[n*2+1] = p1; }
}

// per node: ONLINE single-pass max+denom, 4-edge-deep loads
__global__ void k_stats2(const float* __restrict__ att2, const int* __restrict__ rowptr,
                         const int* __restrict__ esrc, float* __restrict__ stat2){
  int n = blockIdx.x*256 + threadIdx.x;
  if (n >= N_NODESC) return;
  float ad = att2[n*2+1];
  int b = rowptr[n], e = rowptr[n+1];
  float m = -1e30f, den = 0.f;
  for (int p = b; p < e; p += 4){
    int c = e - p; if (c > 4) c = 4;
    float v[4];
    #pragma unroll
    for (int j = 0; j < 4; j++){ int s = esrc[p + (j < c ? j : 0)]; v[j] = att2[s*2]; }
    #pragma unroll
    for (int j = 0; j < 4; j++){
      if (j < c){
        float ev = lrelu(v[j] + ad);
        float mn = fmaxf(m, ev);
        den = den*__expf(m - mn) + __expf(ev - mn);
        m = mn;
      }
    }
  }
  stat2[n*2] = m;
  stat2[n*2+1] = 1.f/(den + 1e-16f);
}

// wave per node, 4-edge-deep coalesced pair gathers; fp32 h2 + sigmoid gate
__global__ void k_agg2(const ushort_t* __restrict__ h2pre,
                       const float* __restrict__ att2,
                       const float* __restrict__ stat2, const int* __restrict__ rowptr,
                       const int* __restrict__ esrc, const float* __restrict__ b2,
                       const float* __restrict__ w_gate, const float* __restrict__ b_gate,
                       float* __restrict__ h2, float* __restrict__ wnode){
  int n = blockIdx.x*4 + (threadIdx.x >> 6);
  int l = threadIdx.x & 63;
  if (n >= N_NODESC) return;
  float ad = att2[n*2+1], m = stat2[n*2], rd = stat2[n*2+1];
  int b = rowptr[n], e = rowptr[n+1];
  float a0 = 0.f, a1 = 0.f;
  for (int p = b; p < e; p += 4){
    int c = e - p; if (c > 4) c = 4;
    int ss[4];
    #pragma unroll
    for (int j = 0; j < 4; j++) ss[j] = esrc[p + (j < c ? j : 0)];
    unsigned u[4]; float at[4];
    #pragma unroll
    for (int j = 0; j < 4; j++) u[j] = *(const unsigned*)(h2pre + (size_t)ss[j]*OUT2C + 2*l);
    #pragma unroll
    for (int j = 0; j < 4; j++) at[j] = att2[ss[j]*2];
    #pragma unroll
    for (int j = 0; j < 4; j++){
      if (j < c){
        float alpha = __expf(lrelu(at[j] + ad) - m) * rd;
        a0 += alpha * bf2f((ushort_t)(u[j] & 0xffffu));
        a1 += alpha * bf2f((ushort_t)(u[j] >> 16));
      }
    }
  }
  float v0 = fmaxf(a0 + b2[2*l],   0.f);
  float v1 = fmaxf(a1 + b2[2*l+1], 0.f);
  float2 hv; hv.x = v0; hv.y = v1;
  *(float2*)(h2 + (size_t)n*OUT2C + 2*l) = hv;
  float pp = v0*w_gate[2*l] + v1*w_gate[2*l+1];
  #pragma unroll
  for (int off = 32; off; off >>= 1) pp += __shfl_xor(pp, off);
  if (l == 0) wnode[n] = 1.f/(1.f + __expf(-(pp + b_gate[0])));
}

// one block per graph: weighted-sum + max readout, bf16 out into xcb[:, 0:256]
__global__ __launch_bounds__(128) void k_readout(const float* __restrict__ h2,
                                                 const float* __restrict__ wnode,
                                                 const int* __restrict__ batch,
                                                 ushort_t* __restrict__ xcb){
  __shared__ int lohi[2];
  int g = blockIdx.x, t = threadIdx.x;
  if (t == 0){
    int lo = 0, hi = N_NODESC;
    while (lo < hi){ int mid = (lo+hi) >> 1; if (batch[mid] < g) lo = mid+1; else hi = mid; }
    lohi[0] = lo;
    int lo2 = lo; hi = N_NODESC;
    while (lo2 < hi){ int mid = (lo2+hi) >> 1; if (batch[mid] < g+1) lo2 = mid+1; else hi = mid; }
    lohi[1] = lo2;
  }
  __syncthreads();
  int lo = lohi[0], hi = lohi[1];
  float sum = 0.f, mx = 0.f;
  for (int n = lo; n < hi; n++){
    float v = h2[(size_t)n*OUT2C + t];
    sum += v * wnode[n];
    mx = fmaxf(mx, v);
  }
  xcb[(size_t)g*512 + t] = f2bf(sum);
  xcb[(size_t)g*512 + 128 + t] = f2bf(mx);
}

__global__ void k_final(const ushort_t* __restrict__ f2b, const float* __restrict__ W_out,
                        const float* __restrict__ b_out, float* __restrict__ out){
  int g = blockIdx.x*4 + (threadIdx.x >> 6);
  int l = threadIdx.x & 63;
  if (g >= N_GRAPHSC) return;
  float s = 0.f;
  #pragma unroll
  for (int k = 0; k < 4; k++) s += bf2f(f2b[(size_t)g*256 + l + 64*k]) * W_out[l + 64*k];
  #pragma unroll
  for (int off = 32; off; off >>= 1) s += __shfl_xor(s, off);
  if (l == 0) out[g] = s + b_out[0];
}

extern "C" void kernel_launch(void* const* d_in, const int* in_sizes, int n_in,
                              void* d_out, int out_size, void* d_ws, size_t ws_size,
                              hipStream_t stream) {
  const float* x      = (const float*)d_in[0];
  const int*   ei     = (const int*)d_in[1];
  const int*   batch  = (const int*)d_in[2];
  const float* target = (const float*)d_in[3];
  const float* W1     = (const float*)d_in[4];
  const float* a_src1 = (const float*)d_in[5];
  const float* a_dst1 = (const float*)d_in[6];
  const float* b1     = (const float*)d_in[7];
  const float* W2     = (const float*)d_in[8];
  const float* a_src2 = (const float*)d_in[9];
  const float* a_dst2 = (const float*)d_in[10];
  const float* b2     = (const float*)d_in[11];
  const float* w_gate = (const float*)d_in[12];
  const float* b_gate = (const float*)d_in[13];
  const float* W_xt   = (const float*)d_in[14];
  const float* b_xt   = (const float*)d_in[15];
  const float* W_fc1  = (const float*)d_in[16];
  const float* b_fc1  = (const float*)d_in[17];
  const float* W_fc2  = (const float*)d_in[18];
  const float* b_fc2  = (const float*)d_in[19];
  const float* W_out  = (const float*)d_in[20];
  const float* b_out  = (const float*)d_in[21];
  float* out = (float*)d_out;

  // ---- adaptive chunking so the carve fits ws_size ----
  const size_t MB = (size_t)1 << 20;
  int C;
  if      (ws_size >= 410*MB) C = 1;
  else if (ws_size >= 245*MB) C = 2;
  else if (ws_size >= 165*MB) C = 4;
  else                        C = 8;
  const int R = N_NODESC / C;

  char* p = (char*)d_ws;
  auto carve = [&](size_t bytes) -> char* {
    char* r = p; p += (bytes + 255) & ~(size_t)255; return r;
  };
  int*   deg    = (int*)  carve((size_t)N_NODESC*4);
  int*   rowptr = (int*)  carve((size_t)(N_NODESC+1)*4);
  int*   cnt    = (int*)  carve((size_t)N_NODESC*4);
  int*   esrc   = (int*)  carve((size_t)E_TOTC*4);
  int*   bsum   = (int*)  carve(128*4);
  float* Wa1    = (float*)carve((size_t)F_INC*20*4);
  float* att1   = (float*)carve((size_t)N_NODESC*20*4);
  float* stat1  = (float*)carve((size_t)N_NODESC*20*4);
  float* att2   = (float*)carve((size_t)N_NODESC*2*4);
  float* stat2  = (float*)carve((size_t)N_NODESC*2*4);
  float* wnode  = (float*)carve((size_t)N_NODESC*4);
  ushort_t* W1t   = (ushort_t*)carve((size_t)HEADS1C*80*96*2);
  ushort_t* W2t   = (ushort_t*)carve((size_t)OUT2C*800*2);
  ushort_t* Wxtt  = (ushort_t*)carve((size_t)256*1280*2);
  ushort_t* Wfc1t = (ushort_t*)carve((size_t)1024*512*2);
  ushort_t* Wfc2t = (ushort_t*)carve((size_t)256*1024*2);
  ushort_t* tb    = (ushort_t*)carve((size_t)N_GRAPHSC*1280*2);
  ushort_t* h2pre = (ushort_t*)carve((size_t)N_NODESC*OUT2C*2);
  ushort_t* xcb   = (ushort_t*)carve((size_t)N_GRAPHSC*512*2);
  ushort_t* f1b   = (ushort_t*)carve((size_t)N_GRAPHSC*1024*2);
  ushort_t* f2b   = (ushort_t*)carve((size_t)N_GRAPHSC*256*2);
  size_t big_bytes = (size_t)R*F1C*2*2 + 4096;          // zc + h1c (bf16) + overread slack
  size_t h2_bytes  = (size_t)N_NODESC*OUT2C*4;          // h2 (fp32)
  char*  BIG = carve(big_bytes > h2_bytes ? big_bytes : h2_bytes);
  ushort_t* zc  = (ushort_t*)BIG;
  ushort_t* h1c = zc + (size_t)R*F1C;
  float* h2 = (float*)BIG;   // overlays zc/h1c AFTER layer-1/2 GEMMs are done

  hipMemsetAsync(deg, 0, (size_t)N_NODESC*4, stream);
  hipMemsetAsync(cnt, 0, (size_t)N_NODESC*4, stream);

  // CSR by destination (self-loops appended) + canonical neighbor order
  k_deg<<<(E_TOTC+255)/256, 256, 0, stream>>>(ei, deg);
  int nb = (N_NODESC + 1023)/1024;
  k_scan1<<<nb, 1024, 0, stream>>>(deg, rowptr, bsum);
  k_scan2<<<1, 64, 0, stream>>>(bsum, rowptr, nb);
  k_scan3<<<nb, 1024, 0, stream>>>(rowptr, bsum);
  k_scatter<<<(E_TOTC+255)/256, 256, 0, stream>>>(ei, rowptr, cnt, esrc);
  k_sortadj<<<(N_NODESC+255)/256, 256, 0, stream>>>(rowptr, esrc);

  // weight prep (bf16 transposed, zero-padded) + target cast
  k_prepW1<<<(HEADS1C*80*96+255)/256, 256, 0, stream>>>(W1, W1t);
  k_prepWt<<<(OUT2C*800+255)/256, 256, 0, stream>>>(W2, W2t, F1C, OUT2C, 800);
  k_prepWt<<<(256*1280+255)/256, 256, 0, stream>>>(W_xt, Wxtt, 1280, 256, 1280);
  k_prepWt<<<(1024*512+255)/256, 256, 0, stream>>>(W_fc1, Wfc1t, 512, 1024, 512);
  k_prepWt<<<(256*1024+255)/256, 256, 0, stream>>>(W_fc2, Wfc2t, 1024, 256, 1024);
  k_cast_bf<<<((N_GRAPHSC*1280)+255)/256, 256, 0, stream>>>(target, tb, N_GRAPHSC*1280);

  // layer-1 attention logits via folded weights
  k_wa1<<<(F_INC*20+255)/256, 256, 0, stream>>>(W1, a_src1, a_dst1, Wa1);
  k_att1<<<(N_NODESC*20+255)/256, 256, 0, stream>>>(x, Wa1, att1);
  k_stats1<<<(N_NODESC*HEADS1C+255)/256, 256, 0, stream>>>(att1, rowptr, esrc, stat1);

  // layer-1 (chunked): agg -> zc; MFMA per-head GEMM+b1+elu -> h1c; h1c@W2 -> h2pre
  for (int c = 0; c < C; c++){
    int base = c*R;
    k_agg1<<<R, 64, 0, stream>>>(x, att1, stat1, rowptr, esrc, zc, base);
    // K = 78 -> KB=96, KVAL=14; BM=128 (2 row groups/wave)
    mfma_gemm<128,80,5,96,14,2,true><<<dim3((R+127)/128, 1, HEADS1C), 256, 0, stream>>>(
        zc, W1t, b1, h1c, R, D1C, F1C, F1C,
        /*zsA*/D1C, /*zsBt*/80*96, /*zsC*/D1C, /*zsBias*/D1C);
    // K = 780 -> KB=800, KVAL=12; BM=128
    mfma_gemm<128,128,8,800,12,0,false><<<dim3((R+127)/128, 1, 1), 256, 0, stream>>>(
        h1c, W2t, nullptr, h2pre + (size_t)base*OUT2C, R, OUT2C, F1C, OUT2C,
        0, 0, 0, 0);
  }

  // layer-2 attention + aggregation (h2 overlays the dead zc/h1c region)
  k_att2<<<(N_NODESC+3)/4, 256, 0, stream>>>(h2pre, a_src2, a_dst2, att2);
  k_stats2<<<(N_NODESC+255)/256, 256, 0, stream>>>(att2, rowptr, esrc, stat2);
  k_agg2<<<(N_NODESC+3)/4, 256, 0, stream>>>(h2pre, att2, stat2, rowptr, esrc,
                                             b2, w_gate, b_gate, h2, wnode);

  // readout (bf16) + MLP head via MFMA (BM=64; K multiples of 32 -> KVAL=32)
  k_readout<<<N_GRAPHSC, 128, 0, stream>>>(h2, wnode, batch, xcb);
  mfma_gemm<64,128,8,1280,32,0,true><<<dim3(N_GRAPHSC/64, 256/128, 1), 256, 0, stream>>>(
      tb, Wxtt, b_xt, xcb + 256, N_GRAPHSC, 256, 1280, 512, 0,0,0,0);
  mfma_gemm<64,128,8,512,32,1,true><<<dim3(N_GRAPHSC/64, 1024/128, 1), 256, 0, stream>>>(
      xcb, Wfc1t, b_fc1, f1b, N_GRAPHSC, 1024, 512, 1024, 0,0,0,0);
  mfma_gemm<64,128,8,1024,32,1,true><<<dim3(N_GRAPHSC/64, 256/128, 1), 256, 0, stream>>>(
      f1b, Wfc2t, b_fc2, f2b, N_GRAPHSC, 256, 1024, 256, 0,0,0,0);
  k_final<<<(N_GRAPHSC+3)/4, 256, 0, stream>>>(f2b, W_out, b_out, out);
}